// Round 4
// baseline (252.177 us; speedup 1.0000x reference)
//
#include <hip/hip_runtime.h>

typedef float fx4 __attribute__((ext_vector_type(4)));   // native vec type for nontemporal builtin

__device__ __forceinline__ void nt_store4(float4* p, float4 v) {
    fx4 vv = {v.x, v.y, v.z, v.w};
    __builtin_nontemporal_store(vv, (fx4*)p);
}

// Quad permute via DPP (VALU, no LDS/DS, no lgkmcnt): out[lane] = in[quad[lane&3]]
template<int CTRL>
__device__ __forceinline__ float qperm(float v) {
    return __int_as_float(__builtin_amdgcn_update_dpp(
        0, __float_as_int(v), CTRL, 0xF, 0xF, true));
}
template<int CTRL>
__device__ __forceinline__ float4 qperm4(float4 v) {
    float4 r;
    r.x = qperm<CTRL>(v.x);
    r.y = qperm<CTRL>(v.y);
    r.z = qperm<CTRL>(v.z);
    r.w = qperm<CTRL>(v.w);
    return r;
}

// quad_perm ctrl byte: [1:0]=src for lane0, [3:2]=lane1, [5:4]=lane2, [7:6]=lane3
#define ROT1 0xC9   // [1,2,0,3]
#define ROT2 0xD2   // [2,0,1,3]
#define BC0  0x00   // broadcast lane 0
#define BC1  0x55   // broadcast lane 1
#define BC2  0xAA   // broadcast lane 2
#define BC3  0xFF   // broadcast lane 3

// Rodrigues in cyclic form, one output row per lane (4 lanes per pose).
// All 6 xi scalars arrive via DPP broadcast from the quad's cooperative load.
__device__ __forceinline__ float4 compose_row(
    float2 f0, float2 f1, float2 f2_,   // lane-uniform after broadcast: (t0,t1),(t2,w0),(w1,w2)
    float4 pr, int r)
{
    float t0 = f0.x, t1 = f0.y, t2 = f1.x;
    float w0 = f1.y, w1 = f2_.x, w2 = f2_.y;

    // A = sin(t)/t, B = (1-cos(t))/t^2, series in x = t^2
    float x = w0 * w0 + w1 * w1 + w2 * w2;
    float A, B;
    if (__builtin_expect(x < 2.25f, 1)) {
        // |err| < ~1.5e-6 for theta < 1.5; series limit == reference small-angle branch
        A = 1.0f + x * (-1.0f / 6.0f  + x * (1.0f / 120.0f + x * (-1.0f / 5040.0f  + x * (1.0f / 362880.0f))));
        B = 0.5f + x * (-1.0f / 24.0f + x * (1.0f / 720.0f + x * (-1.0f / 40320.0f + x * (1.0f / 3628800.0f))));
    } else {
        float th = sqrtf(x);
        A = sinf(th) / th;
        B = (1.0f - cosf(th)) / x;
    }

    float wr = (r == 0) ? w0 : (r == 1) ? w1 : w2;
    float tr = (r == 0) ? t0 : (r == 1) ? t1 : (r == 2) ? t2 : 0.0f;

    float wa = qperm<ROT1>(wr);   // w[(r+1)%3]
    float wb = qperm<ROT2>(wr);   // w[(r+2)%3]

    float4 Pa = qperm4<ROT1>(pr); // pose row (r+1)%3
    float4 Pb = qperm4<ROT2>(pr); // pose row (r+2)%3
    float4 P3 = qperm4<BC3>(pr);  // pose row 3

    float diag = 1.0f - B * (wa * wa + wb * wb);
    float off1 = B * wr * wa - A * wb;
    float off2 = B * wr * wb + A * wa;
    if (r == 3) { diag = 1.0f; off1 = 0.0f; off2 = 0.0f; }  // T row3 = [0,0,0,1]

    float4 o;
    o.x = diag * pr.x + off1 * Pa.x + off2 * Pb.x + tr * P3.x;
    o.y = diag * pr.y + off1 * Pa.y + off2 * Pb.y + tr * P3.y;
    o.z = diag * pr.z + off1 * Pa.z + off2 * Pb.z + tr * P3.z;
    o.w = diag * pr.w + off1 * Pa.w + off2 * Pb.w + tr * P3.w;
    return o;
}

// Two poses per thread (elements i and i+n2; both streams wave-coalesced).
// Per thread: 2x float2 xi loads (cooperative within quad) + 2x float4 pose loads,
// all issued before any use -> 2x the independent bytes in flight per wave,
// 6 VMEM instructions per 2 poses (was 10).
__global__ __launch_bounds__(256) void se3_compose_kernel(
    const float* __restrict__ xi,
    const float4* __restrict__ poses4,   // flat float4 view, length 4*n
    float4* __restrict__ out4,           // flat float4 view, length 4*n
    int n2)                              // = 2*n (half the float4 elements; multiple of 4)
{
    int i = blockIdx.x * blockDim.x + threadIdx.x;
    if (i >= n2) return;

    int r = i & 3;
    long long p0 = (long long)(i >> 2);
    long long p1 = p0 + (n2 >> 2);

    // ---- cooperative xi load: lane r of quad loads x2[min(r,2)] for each pose ----
    int rc = (r < 2) ? r : 2;
    const float2* xA = (const float2*)(xi + 6ll * p0);
    const float2* xB = (const float2*)(xi + 6ll * p1);
    float2 fa = xA[rc];
    float2 fb = xB[rc];

    // ---- pose rows: two independent coalesced float4 streams ----
    float4 pr0 = poses4[i];
    float4 pr1 = poses4[i + n2];

    // ---- distribute xi within the quad (DPP broadcasts, no LDS) ----
    float2 a0; a0.x = qperm<BC0>(fa.x); a0.y = qperm<BC0>(fa.y);   // (t0,t1) pose0
    float2 a1; a1.x = qperm<BC1>(fa.x); a1.y = qperm<BC1>(fa.y);   // (t2,w0) pose0
    float2 a2; a2.x = qperm<BC2>(fa.x); a2.y = qperm<BC2>(fa.y);   // (w1,w2) pose0
    float2 b0; b0.x = qperm<BC0>(fb.x); b0.y = qperm<BC0>(fb.y);   // (t0,t1) pose1
    float2 b1; b1.x = qperm<BC1>(fb.x); b1.y = qperm<BC1>(fb.y);   // (t2,w0) pose1
    float2 b2; b2.x = qperm<BC2>(fb.x); b2.y = qperm<BC2>(fb.y);   // (w1,w2) pose1

    float4 o0 = compose_row(a0, a1, a2, pr0, r);
    float4 o1 = compose_row(b0, b1, b2, pr1, r);

    nt_store4(&out4[i],      o0);
    nt_store4(&out4[i + n2], o1);
}

extern "C" void kernel_launch(void* const* d_in, const int* in_sizes, int n_in,
                              void* d_out, int out_size, void* d_ws, size_t ws_size,
                              hipStream_t stream) {
    const float*  xi     = (const float*)d_in[0];
    const float4* poses4 = (const float4*)d_in[1];
    float4*       out4   = (float4*)d_out;

    int n  = in_sizes[0] / 6;  // N = 2,000,000
    int n2 = 2 * n;            // half the total float4 elements

    const int block = 256;
    const int grid  = (n2 + block - 1) / block;
    se3_compose_kernel<<<grid, block, 0, stream>>>(xi, poses4, out4, n2);
}